// Round 1
// baseline (1112.712 us; speedup 1.0000x reference)
//
#include <hip/hip_runtime.h>
#include <hip/hip_bf16.h>
#include <math.h>

// Problem constants: B=4, S=1024, E=1024, H=16, Dh=64
#define BB 4
#define SS 1024
#define EE 1024
#define HH 16
#define DH 64
#define BH (BB*HH)          // 64
#define OUT0_SZ (BB*SS*EE)  // 4194304
#define QKV_SZ  (BH*SS*DH)  // 4194304 per tensor

// ---------------------------------------------------------------------------
// Generic 128x128x16 fp32 tiled GEMM: C = A(MxK) @ B(KxN) + bias
// MODE 0: scatter output into qkv workspace [3][BH][S][Dh]
// MODE 1: plain row-major output with bias (proj)
// ---------------------------------------------------------------------------
template<int MODE>
__global__ __launch_bounds__(256)
void gemm128(const float* __restrict__ A, const float* __restrict__ B,
             const float* __restrict__ bias, float* __restrict__ out,
             int M, int N, int K) {
  __shared__ float As[16][132];
  __shared__ float Bs[16][132];
  const int tid = threadIdx.x;
  const int n0 = blockIdx.x * 128;
  const int m0 = blockIdx.y * 128;
  const int ty = tid >> 4, tx = tid & 15;
  const int mrow = ty * 8, ncol = tx * 8;
  float acc[8][8] = {};

  for (int kt = 0; kt < K; kt += 16) {
    __syncthreads();
    // A tile: rows m0..+127, cols kt..+15, transposed into As[k][m]
#pragma unroll
    for (int i = 0; i < 2; i++) {
      int fidx = tid + i * 256;           // float4 index, 512 total
      int r = fidx >> 2, c4 = fidx & 3;
      float4 av = *(const float4*)&A[(size_t)(m0 + r) * K + kt + c4 * 4];
      As[c4 * 4 + 0][r] = av.x; As[c4 * 4 + 1][r] = av.y;
      As[c4 * 4 + 2][r] = av.z; As[c4 * 4 + 3][r] = av.w;
    }
    // B tile: rows kt..+15, cols n0..+127, natural layout
#pragma unroll
    for (int i = 0; i < 2; i++) {
      int fidx = tid + i * 256;
      int r = fidx >> 5, c4 = fidx & 31;
      *(float4*)&Bs[r][c4 * 4] = *(const float4*)&B[(size_t)(kt + r) * N + n0 + c4 * 4];
    }
    __syncthreads();
#pragma unroll
    for (int kk = 0; kk < 16; kk++) {
      float a[8], b[8];
      *(float4*)&a[0] = *(const float4*)&As[kk][mrow];
      *(float4*)&a[4] = *(const float4*)&As[kk][mrow + 4];
      *(float4*)&b[0] = *(const float4*)&Bs[kk][ncol];
      *(float4*)&b[4] = *(const float4*)&Bs[kk][ncol + 4];
#pragma unroll
      for (int i = 0; i < 8; i++)
#pragma unroll
        for (int j = 0; j < 8; j++)
          acc[i][j] = fmaf(a[i], b[j], acc[i][j]);
    }
  }

#pragma unroll
  for (int i = 0; i < 8; i++) {
    int m = m0 + mrow + i;
#pragma unroll
    for (int j = 0; j < 8; j++) {
      int n = n0 + ncol + j;
      float v = acc[i][j] + bias[n];
      if (MODE == 0) {
        int t = n >> 10, h = (n >> 6) & 15, dh = n & 63;
        int b = m >> 10, s = m & 1023;
        out[(size_t)t * QKV_SZ + ((size_t)((b << 4) + h) * SS + s) * DH + dh] = v;
      } else {
        out[(size_t)m * N + n] = v;
      }
    }
  }
}

// ---------------------------------------------------------------------------
// Batched NT GEMM: logits[bh][m][n] = 0.125 * sum_d Q[bh][m][d]*K[bh][n][d]
// grid: (n-tile 8, m-tile 8, bh 64)
// ---------------------------------------------------------------------------
__global__ __launch_bounds__(256)
void qk_gemm(const float* __restrict__ Q, const float* __restrict__ Kmat,
             float* __restrict__ att) {
  const int bh = blockIdx.z;
  const float* Aq = Q + (size_t)bh * (SS * DH);
  const float* Bk = Kmat + (size_t)bh * (SS * DH);
  float* L = att + (size_t)bh * (SS * SS);
  __shared__ float As[16][132];
  __shared__ float Bs[16][132];
  const int tid = threadIdx.x;
  const int n0 = blockIdx.x * 128;
  const int m0 = blockIdx.y * 128;
  const int ty = tid >> 4, tx = tid & 15;
  const int mrow = ty * 8, ncol = tx * 8;
  float acc[8][8] = {};

  for (int kt = 0; kt < DH; kt += 16) {
    __syncthreads();
#pragma unroll
    for (int i = 0; i < 2; i++) {
      int fidx = tid + i * 256;
      int r = fidx >> 2, c4 = fidx & 3;
      float4 av = *(const float4*)&Aq[(size_t)(m0 + r) * DH + kt + c4 * 4];
      As[c4 * 4 + 0][r] = av.x; As[c4 * 4 + 1][r] = av.y;
      As[c4 * 4 + 2][r] = av.z; As[c4 * 4 + 3][r] = av.w;
    }
#pragma unroll
    for (int i = 0; i < 2; i++) {
      int fidx = tid + i * 256;
      int r = fidx >> 2, c4 = fidx & 3;
      float4 bv = *(const float4*)&Bk[(size_t)(n0 + r) * DH + kt + c4 * 4];
      Bs[c4 * 4 + 0][r] = bv.x; Bs[c4 * 4 + 1][r] = bv.y;
      Bs[c4 * 4 + 2][r] = bv.z; Bs[c4 * 4 + 3][r] = bv.w;
    }
    __syncthreads();
#pragma unroll
    for (int kk = 0; kk < 16; kk++) {
      float a[8], b[8];
      *(float4*)&a[0] = *(const float4*)&As[kk][mrow];
      *(float4*)&a[4] = *(const float4*)&As[kk][mrow + 4];
      *(float4*)&b[0] = *(const float4*)&Bs[kk][ncol];
      *(float4*)&b[4] = *(const float4*)&Bs[kk][ncol + 4];
#pragma unroll
      for (int i = 0; i < 8; i++)
#pragma unroll
        for (int j = 0; j < 8; j++)
          acc[i][j] = fmaf(a[i], b[j], acc[i][j]);
    }
  }

#pragma unroll
  for (int i = 0; i < 8; i++) {
    int m = m0 + mrow + i;
#pragma unroll
    for (int j = 0; j < 8; j++) {
      int n = n0 + ncol + j;
      L[(size_t)m * SS + n] = acc[i][j] * 0.125f;   // exact pow2 scale
    }
  }
}

// ---------------------------------------------------------------------------
// Per-row softmax -> threshold mask (probs > 0.1) with first-index argmax
// fallback -> filtered softmax, in-place on att.  One block (256 thr) per row.
// ---------------------------------------------------------------------------
__global__ __launch_bounds__(256)
void softmax_filter(float* __restrict__ att) {
  float* p = att + (size_t)blockIdx.x * SS;
  const int tid = threadIdx.x;
  const int lane = tid & 63, wv = tid >> 6;

  float4 z4 = *(const float4*)&p[tid * 4];
  float z[4] = {z4.x, z4.y, z4.z, z4.w};

  // local max + first-index argmax (ascending, strict >)
  float m = z[0]; int am = tid * 4;
#pragma unroll
  for (int j = 1; j < 4; j++) if (z[j] > m) { m = z[j]; am = tid * 4 + j; }
  // wave butterfly: larger value wins, tie -> smaller index
#pragma unroll
  for (int off = 32; off >= 1; off >>= 1) {
    float om = __shfl_xor(m, off, 64);
    int oa = __shfl_xor(am, off, 64);
    if (om > m || (om == m && oa < am)) { m = om; am = oa; }
  }
  __shared__ float wm[4]; __shared__ int wa[4];
  __shared__ float wsum[4]; __shared__ float wf[4]; __shared__ int wany[4];
  if (lane == 0) { wm[wv] = m; wa[wv] = am; }
  __syncthreads();
  m = wm[0]; am = wa[0];
#pragma unroll
  for (int w = 1; w < 4; w++) {
    float om = wm[w]; int oa = wa[w];
    if (om > m || (om == m && oa < am)) { m = om; am = oa; }
  }

  float e[4]; float s = 0.f;
#pragma unroll
  for (int j = 0; j < 4; j++) { e[j] = expf(z[j] - m); s += e[j]; }
#pragma unroll
  for (int off = 32; off >= 1; off >>= 1) s += __shfl_xor(s, off, 64);
  if (lane == 0) wsum[wv] = s;
  __syncthreads();
  s = wsum[0] + wsum[1] + wsum[2] + wsum[3];

  bool sel[4]; float fl = 0.f; int anyl = 0;
#pragma unroll
  for (int j = 0; j < 4; j++) {
    sel[j] = (e[j] / s > 0.1f);
    if (sel[j]) { fl += e[j]; anyl = 1; }
  }
#pragma unroll
  for (int off = 32; off >= 1; off >>= 1) fl += __shfl_xor(fl, off, 64);
  int wany_l = __any(anyl);
  if (lane == 0) { wf[wv] = fl; wany[wv] = wany_l; }
  __syncthreads();
  float fs = wf[0] + wf[1] + wf[2] + wf[3];
  int any = wany[0] | wany[1] | wany[2] | wany[3];

  float4 fa;
  float* faf = (float*)&fa;
#pragma unroll
  for (int j = 0; j < 4; j++) {
    if (any) faf[j] = sel[j] ? e[j] / fs : 0.f;
    else     faf[j] = (tid * 4 + j == am) ? 1.f : 0.f;
  }
  *(float4*)&p[tid * 4] = fa;
}

// ---------------------------------------------------------------------------
// Batched PV GEMM: ao[b][s][h*64+d] = sum_k fa[bh][s][k] * V[bh][k][d]
// tile 128(m) x 64(n) x 32(k); grid: (m-tile 8, bh 64)
// ---------------------------------------------------------------------------
__global__ __launch_bounds__(256)
void pv_gemm(const float* __restrict__ fa, const float* __restrict__ V,
             float* __restrict__ ao) {
  const int bh = blockIdx.y;
  const int m0 = blockIdx.x * 128;
  const float* Af = fa + (size_t)bh * (SS * SS);
  const float* Bv = V + (size_t)bh * (SS * DH);
  __shared__ float As[32][132];
  __shared__ float Bs[32][68];
  const int tid = threadIdx.x;
  const int ty = tid >> 4, tx = tid & 15;
  const int mrow = ty * 8, ncol = tx * 4;
  float acc[8][4] = {};

  for (int kt = 0; kt < SS; kt += 32) {
    __syncthreads();
#pragma unroll
    for (int i = 0; i < 4; i++) {
      int fidx = tid + i * 256;          // 1024 float4
      int r = fidx >> 3, c4 = fidx & 7;
      float4 av = *(const float4*)&Af[(size_t)(m0 + r) * SS + kt + c4 * 4];
      As[c4 * 4 + 0][r] = av.x; As[c4 * 4 + 1][r] = av.y;
      As[c4 * 4 + 2][r] = av.z; As[c4 * 4 + 3][r] = av.w;
    }
#pragma unroll
    for (int i = 0; i < 2; i++) {
      int fidx = tid + i * 256;          // 512 float4
      int r = fidx >> 4, c4 = fidx & 15;
      *(float4*)&Bs[r][c4 * 4] = *(const float4*)&Bv[(size_t)(kt + r) * DH + c4 * 4];
    }
    __syncthreads();
#pragma unroll
    for (int kk = 0; kk < 32; kk++) {
      float a[8], b[4];
      *(float4*)&a[0] = *(const float4*)&As[kk][mrow];
      *(float4*)&a[4] = *(const float4*)&As[kk][mrow + 4];
      *(float4*)&b[0] = *(const float4*)&Bs[kk][ncol];
#pragma unroll
      for (int i = 0; i < 8; i++)
#pragma unroll
        for (int j = 0; j < 4; j++)
          acc[i][j] = fmaf(a[i], b[j], acc[i][j]);
    }
  }

  const int b = bh >> 4, h = bh & 15;
#pragma unroll
  for (int i = 0; i < 8; i++) {
    int srow = m0 + mrow + i;
#pragma unroll
    for (int j = 0; j < 4; j++) {
      ao[((size_t)((b << 10) + srow)) * EE + (h << 6) + ncol + j] = acc[i][j];
    }
  }
}

// ---------------------------------------------------------------------------
extern "C" void kernel_launch(void* const* d_in, const int* in_sizes, int n_in,
                              void* d_out, int out_size, void* d_ws, size_t ws_size,
                              hipStream_t stream) {
  const float* x      = (const float*)d_in[0];
  const float* w_qkv  = (const float*)d_in[1];
  const float* b_qkv  = (const float*)d_in[2];
  const float* w_proj = (const float*)d_in[3];
  const float* b_proj = (const float*)d_in[4];

  float* out0 = (float*)d_out;                 // [B,S,E]
  float* att  = out0 + OUT0_SZ;                // [B,H,S,S]: logits then filtered_attn

  float* ws = (float*)d_ws;
  float* q  = ws;                              // [BH][S][Dh]
  float* k  = ws + (size_t)QKV_SZ;
  float* v  = ws + (size_t)2 * QKV_SZ;
  float* ao = ws + (size_t)3 * QKV_SZ;         // [B,S,E] attention output

  // 1) qkv = x @ w_qkv + b_qkv, scattered to q/k/v
  gemm128<0><<<dim3(24, 32), 256, 0, stream>>>(x, w_qkv, b_qkv, ws, BB * SS, 3 * EE, EE);
  // 2) logits = (q @ k^T) * scale  -> att region (scratch inside d_out)
  qk_gemm<<<dim3(8, 8, BH), 256, 0, stream>>>(q, k, att);
  // 3) softmax -> threshold/argmax filter -> filtered softmax (in place)
  softmax_filter<<<BH * SS, 256, 0, stream>>>(att);
  // 4) attention output = filtered_attn @ v
  pv_gemm<<<dim3(8, BH), 256, 0, stream>>>(att, v, ao);
  // 5) out = ao @ w_proj + b_proj
  gemm128<1><<<dim3(8, 32), 256, 0, stream>>>(ao, w_proj, b_proj, out0, BB * SS, EE, EE);
}

// Round 3
// 661.398 us; speedup vs baseline: 1.6824x; 1.6824x over previous
//
#include <hip/hip_runtime.h>
#include <math.h>

// B=4, S=1024, E=1024, H=16, Dh=64
#define SS 1024
#define OUT0_SZ (4*1024*1024)

typedef _Float16 f16;
typedef _Float16 h8 __attribute__((ext_vector_type(8)));
typedef _Float16 h4 __attribute__((ext_vector_type(4)));
typedef float f32x4 __attribute__((ext_vector_type(4)));

#define MFMA(a,b,c) __builtin_amdgcn_mfma_f32_16x16x32_f16(a, b, c, 0, 0, 0)

__device__ __forceinline__ void gload_lds16(const void* g, void* l) {
  __builtin_amdgcn_global_load_lds((const __attribute__((address_space(1))) void*)g,
                                   (__attribute__((address_space(3))) void*)l, 16, 0, 0);
}

// ---------------------------------------------------------------------------
// transpose + (optional split) fp32 [K][N] -> f16 [N][K], scaled by `scale`
// ---------------------------------------------------------------------------
template<int SPLIT>
__global__ __launch_bounds__(256)
void transpose_split(const float* __restrict__ in, f16* __restrict__ outHi,
                     f16* __restrict__ outLo, int K, int N, float scale) {
  __shared__ float t[32][33];
  const int n0 = blockIdx.x * 32, k0 = blockIdx.y * 32;
  const int tx = threadIdx.x & 31, ty = threadIdx.x >> 5;   // ty 0..7
#pragma unroll
  for (int j = 0; j < 4; j++)
    t[ty + j * 8][tx] = in[(size_t)(k0 + ty + j * 8) * N + n0 + tx] * scale;
  __syncthreads();
#pragma unroll
  for (int j = 0; j < 4; j++) {
    float v = t[tx][ty + j * 8];
    f16 h = (f16)v;
    size_t idx = (size_t)(n0 + ty + j * 8) * K + k0 + tx;
    outHi[idx] = h;
    if (SPLIT) outLo[idx] = (f16)(v - (float)h);
  }
}

// ---------------------------------------------------------------------------
// V transpose: f16 [bh][1024 s][64 d] -> [bh][64 d][1024 s]
// ---------------------------------------------------------------------------
__global__ __launch_bounds__(256)
void transpose_v(const f16* __restrict__ in, f16* __restrict__ out) {
  __shared__ f16 t[32][33];
  const int bh = blockIdx.z, s0 = blockIdx.x * 32, d0 = blockIdx.y * 32;
  in  += (size_t)bh * 65536;
  out += (size_t)bh * 65536;
  const int tx = threadIdx.x & 31, ty = threadIdx.x >> 5;
#pragma unroll
  for (int j = 0; j < 4; j++)
    t[ty + j * 8][tx] = in[(size_t)(s0 + ty + j * 8) * 64 + d0 + tx];
  __syncthreads();
#pragma unroll
  for (int j = 0; j < 4; j++)
    out[(size_t)(d0 + ty + j * 8) * 1024 + s0 + tx] = t[tx][ty + j * 8];
}

// ---------------------------------------------------------------------------
// QKV GEMM: split-f16 MFMA.  x fp32 [4096][1024] (A, reg-staged, scale 2^6);
// WhiT/WloT f16 [3072 n][1024 k] (B, global_load_lds, pre-scaled 2^12).
// acc * 2^-18 + bias -> scatter: q,k re-split (scale 2^6) to Qhi/Qlo/Khi/Klo;
// v -> plain f16 Vf [bh][s][d].
// ---------------------------------------------------------------------------
__global__ __launch_bounds__(256)
void qkv_gemm(const float* __restrict__ x, const f16* __restrict__ WhiT,
              const f16* __restrict__ WloT, const float* __restrict__ bias,
              f16* __restrict__ Qhi, f16* __restrict__ Qlo,
              f16* __restrict__ Khi, f16* __restrict__ Klo, f16* __restrict__ Vf) {
  __shared__ __align__(16) f16 Ah[128 * 32], Al[128 * 32], Bh[128 * 32], Bl[128 * 32];
  const int tid = threadIdx.x, w = tid >> 6, l = tid & 63;
  const int n0 = blockIdx.x * 128, m0 = blockIdx.y * 128;
  const int wr = (w & 1) * 64, wc = (w >> 1) * 64;
  const int fr = l & 15, fq = l >> 4;
  f32x4 acc[4][4] = {};

  for (int kt = 0; kt < 1024; kt += 32) {
    __syncthreads();
#pragma unroll
    for (int i = 0; i < 2; i++) {
      int row = w * 32 + i * 16 + (l >> 2);
      size_t srcoff = (size_t)(n0 + row) * 1024 + kt + (l & 3) * 8;
      gload_lds16(WhiT + srcoff, Bh + w * 1024 + i * 512);
      gload_lds16(WloT + srcoff, Bl + w * 1024 + i * 512);
    }
#pragma unroll
    for (int r4 = 0; r4 < 4; r4++) {
      int f = r4 * 256 + tid;                  // float4 index
      int row = f >> 3, c4 = (f & 7) * 4;
      float4 xv = *(const float4*)&x[(size_t)(m0 + row) * 1024 + kt + c4];
      float vv[4] = {xv.x, xv.y, xv.z, xv.w};
      h4 hh, ll;
#pragma unroll
      for (int j = 0; j < 4; j++) {
        float sv = vv[j] * 64.f;
        f16 h = (f16)sv;
        hh[j] = h; ll[j] = (f16)(sv - (float)h);
      }
      *(h4*)&Ah[row * 32 + c4] = hh;
      *(h4*)&Al[row * 32 + c4] = ll;
    }
    __syncthreads();
    h8 ah[4], al[4], bh[4], bl[4];
#pragma unroll
    for (int m = 0; m < 4; m++) {
      ah[m] = *(h8*)&Ah[(wr + m * 16 + fr) * 32 + fq * 8];
      al[m] = *(h8*)&Al[(wr + m * 16 + fr) * 32 + fq * 8];
    }
#pragma unroll
    for (int n = 0; n < 4; n++) {
      bh[n] = *(h8*)&Bh[(wc + n * 16 + fr) * 32 + fq * 8];
      bl[n] = *(h8*)&Bl[(wc + n * 16 + fr) * 32 + fq * 8];
    }
#pragma unroll
    for (int m = 0; m < 4; m++)
#pragma unroll
      for (int n = 0; n < 4; n++) {
        acc[m][n] = MFMA(ah[m], bh[n], acc[m][n]);
        acc[m][n] = MFMA(al[m], bh[n], acc[m][n]);
        acc[m][n] = MFMA(ah[m], bl[n], acc[m][n]);
      }
  }

#pragma unroll
  for (int m = 0; m < 4; m++)
#pragma unroll
    for (int n = 0; n < 4; n++)
#pragma unroll
      for (int j = 0; j < 4; j++) {
        int row = m0 + wr + m * 16 + fq * 4 + j;
        int col = n0 + wc + n * 16 + fr;
        float val = acc[m][n][j] * (1.f / 262144.f) + bias[col];
        int t = col >> 10, h = (col >> 6) & 15, d = col & 63;
        int b = row >> 10, s = row & 1023;
        size_t idx = ((size_t)(b * 16 + h) * 1024 + s) * 64 + d;
        if (t == 0) { f16 hh = (f16)(val * 64.f); Qhi[idx] = hh; Qlo[idx] = (f16)(val * 64.f - (float)hh); }
        else if (t == 1) { f16 hh = (f16)(val * 64.f); Khi[idx] = hh; Klo[idx] = (f16)(val * 64.f - (float)hh); }
        else Vf[idx] = (f16)val;
      }
}

// ---------------------------------------------------------------------------
// QK^T: batched split-f16 MFMA.  Qhi/Qlo (A), Khi/Klo (B, NT layout), K=64.
// logits = acc * 2^-12(descale) * 0.125 = acc * 2^-15 -> fp32 att
// ---------------------------------------------------------------------------
__global__ __launch_bounds__(256)
void qk_gemm(const f16* __restrict__ Qhi, const f16* __restrict__ Qlo,
             const f16* __restrict__ Khi, const f16* __restrict__ Klo,
             float* __restrict__ att) {
  __shared__ __align__(16) f16 Ah[128 * 32], Al[128 * 32], Bh[128 * 32], Bl[128 * 32];
  const int bh = blockIdx.z;
  const size_t off = (size_t)bh * 65536;
  const int tid = threadIdx.x, w = tid >> 6, l = tid & 63;
  const int n0 = blockIdx.x * 128, m0 = blockIdx.y * 128;
  const int wr = (w & 1) * 64, wc = (w >> 1) * 64;
  const int fr = l & 15, fq = l >> 4;
  f32x4 acc[4][4] = {};

  for (int kt = 0; kt < 64; kt += 32) {
    __syncthreads();
#pragma unroll
    for (int i = 0; i < 2; i++) {
      int row = w * 32 + i * 16 + (l >> 2);
      int co = kt + (l & 3) * 8;
      gload_lds16(Qhi + off + (size_t)(m0 + row) * 64 + co, Ah + w * 1024 + i * 512);
      gload_lds16(Qlo + off + (size_t)(m0 + row) * 64 + co, Al + w * 1024 + i * 512);
      gload_lds16(Khi + off + (size_t)(n0 + row) * 64 + co, Bh + w * 1024 + i * 512);
      gload_lds16(Klo + off + (size_t)(n0 + row) * 64 + co, Bl + w * 1024 + i * 512);
    }
    __syncthreads();
    h8 ah[4], al[4], bh[4], bl[4];
#pragma unroll
    for (int m = 0; m < 4; m++) {
      ah[m] = *(h8*)&Ah[(wr + m * 16 + fr) * 32 + fq * 8];
      al[m] = *(h8*)&Al[(wr + m * 16 + fr) * 32 + fq * 8];
    }
#pragma unroll
    for (int n = 0; n < 4; n++) {
      bh[n] = *(h8*)&Bh[(wc + n * 16 + fr) * 32 + fq * 8];
      bl[n] = *(h8*)&Bl[(wc + n * 16 + fr) * 32 + fq * 8];
    }
#pragma unroll
    for (int m = 0; m < 4; m++)
#pragma unroll
      for (int n = 0; n < 4; n++) {
        acc[m][n] = MFMA(ah[m], bh[n], acc[m][n]);
        acc[m][n] = MFMA(al[m], bh[n], acc[m][n]);
        acc[m][n] = MFMA(ah[m], bl[n], acc[m][n]);
      }
  }

  float* L = att + (size_t)bh * 1048576;
#pragma unroll
  for (int m = 0; m < 4; m++)
#pragma unroll
    for (int n = 0; n < 4; n++)
#pragma unroll
      for (int j = 0; j < 4; j++) {
        int row = m0 + wr + m * 16 + fq * 4 + j;
        int col = n0 + wc + n * 16 + fr;
        L[(size_t)row * 1024 + col] = acc[m][n][j] * (1.f / 32768.f);
      }
}

// ---------------------------------------------------------------------------
// softmax -> threshold(0.1)/argmax-fallback filter -> filtered softmax, in place
// (unchanged from validated round-1 kernel)
// ---------------------------------------------------------------------------
__global__ __launch_bounds__(256)
void softmax_filter(float* __restrict__ att) {
  float* p = att + (size_t)blockIdx.x * SS;
  const int tid = threadIdx.x;
  const int lane = tid & 63, wv = tid >> 6;

  float4 z4 = *(const float4*)&p[tid * 4];
  float z[4] = {z4.x, z4.y, z4.z, z4.w};

  float m = z[0]; int am = tid * 4;
#pragma unroll
  for (int j = 1; j < 4; j++) if (z[j] > m) { m = z[j]; am = tid * 4 + j; }
#pragma unroll
  for (int off = 32; off >= 1; off >>= 1) {
    float om = __shfl_xor(m, off, 64);
    int oa = __shfl_xor(am, off, 64);
    if (om > m || (om == m && oa < am)) { m = om; am = oa; }
  }
  __shared__ float wm[4]; __shared__ int wa[4];
  __shared__ float wsum[4]; __shared__ float wf[4]; __shared__ int wany[4];
  if (lane == 0) { wm[wv] = m; wa[wv] = am; }
  __syncthreads();
  m = wm[0]; am = wa[0];
#pragma unroll
  for (int w = 1; w < 4; w++) {
    float om = wm[w]; int oa = wa[w];
    if (om > m || (om == m && oa < am)) { m = om; am = oa; }
  }

  float e[4]; float s = 0.f;
#pragma unroll
  for (int j = 0; j < 4; j++) { e[j] = expf(z[j] - m); s += e[j]; }
#pragma unroll
  for (int off = 32; off >= 1; off >>= 1) s += __shfl_xor(s, off, 64);
  if (lane == 0) wsum[wv] = s;
  __syncthreads();
  s = wsum[0] + wsum[1] + wsum[2] + wsum[3];

  bool sel[4]; float fl = 0.f; int anyl = 0;
#pragma unroll
  for (int j = 0; j < 4; j++) {
    sel[j] = (e[j] / s > 0.1f);
    if (sel[j]) { fl += e[j]; anyl = 1; }
  }
#pragma unroll
  for (int off = 32; off >= 1; off >>= 1) fl += __shfl_xor(fl, off, 64);
  int wany_l = __any(anyl);
  if (lane == 0) { wf[wv] = fl; wany[wv] = wany_l; }
  __syncthreads();
  float fs = wf[0] + wf[1] + wf[2] + wf[3];
  int any = wany[0] | wany[1] | wany[2] | wany[3];

  float4 fa;
  float* faf = (float*)&fa;
#pragma unroll
  for (int j = 0; j < 4; j++) {
    if (any) faf[j] = sel[j] ? e[j] / fs : 0.f;
    else     faf[j] = (tid * 4 + j == am) ? 1.f : 0.f;
  }
  *(float4*)&p[tid * 4] = fa;
}

// ---------------------------------------------------------------------------
// PV: batched f16 MFMA.  A = filtered_attn fp32 (reg-staged->f16; one-hots
// are exact), B = Vt f16 [bh][64 d][1024 s].  Tile 128x64. Out: ao16 f16.
// ---------------------------------------------------------------------------
__global__ __launch_bounds__(256)
void pv_gemm(const float* __restrict__ att, const f16* __restrict__ Vt,
             f16* __restrict__ ao) {
  __shared__ __align__(16) f16 A[128 * 32], B[64 * 32];
  const int bh = blockIdx.y, m0 = blockIdx.x * 128;
  const float* fa = att + (size_t)bh * 1048576;
  const f16* Vb = Vt + (size_t)bh * 65536;
  const int tid = threadIdx.x, w = tid >> 6, l = tid & 63;
  const int wr = (w & 1) * 64, wc = (w >> 1) * 32;
  const int fr = l & 15, fq = l >> 4;
  f32x4 acc[4][2] = {};

  for (int kt = 0; kt < 1024; kt += 32) {
    __syncthreads();
    {
      int row = w * 16 + (l >> 2);
      gload_lds16(Vb + (size_t)row * 1024 + kt + (l & 3) * 8, B + w * 512);
    }
#pragma unroll
    for (int r4 = 0; r4 < 4; r4++) {
      int f = r4 * 256 + tid;
      int row = f >> 3, c4 = (f & 7) * 4;
      float4 pv4 = *(const float4*)&fa[(size_t)(m0 + row) * 1024 + kt + c4];
      h4 hh;
      hh[0] = (f16)pv4.x; hh[1] = (f16)pv4.y; hh[2] = (f16)pv4.z; hh[3] = (f16)pv4.w;
      *(h4*)&A[row * 32 + c4] = hh;
    }
    __syncthreads();
    h8 a[4], b[2];
#pragma unroll
    for (int m = 0; m < 4; m++) a[m] = *(h8*)&A[(wr + m * 16 + fr) * 32 + fq * 8];
#pragma unroll
    for (int n = 0; n < 2; n++) b[n] = *(h8*)&B[(wc + n * 16 + fr) * 32 + fq * 8];
#pragma unroll
    for (int m = 0; m < 4; m++)
#pragma unroll
      for (int n = 0; n < 2; n++) acc[m][n] = MFMA(a[m], b[n], acc[m][n]);
  }

  const int b = bh >> 4, h = bh & 15;
#pragma unroll
  for (int m = 0; m < 4; m++)
#pragma unroll
    for (int n = 0; n < 2; n++)
#pragma unroll
      for (int j = 0; j < 4; j++) {
        int s = m0 + wr + m * 16 + fq * 4 + j;
        int d = wc + n * 16 + fr;
        ao[((size_t)(b * 1024 + s)) * 1024 + h * 64 + d] = (f16)acc[m][n][j];
      }
}

// ---------------------------------------------------------------------------
// proj: plain f16 MFMA.  A = ao16 [4096][1024], B = WpT [1024 n][1024 k].
// out fp32 = acc + bias.
// ---------------------------------------------------------------------------
__global__ __launch_bounds__(256)
void proj_gemm(const f16* __restrict__ ao, const f16* __restrict__ WpT,
               const float* __restrict__ bias, float* __restrict__ out) {
  __shared__ __align__(16) f16 A[128 * 32], B[128 * 32];
  const int tid = threadIdx.x, w = tid >> 6, l = tid & 63;
  const int n0 = blockIdx.x * 128, m0 = blockIdx.y * 128;
  const int wr = (w & 1) * 64, wc = (w >> 1) * 64;
  const int fr = l & 15, fq = l >> 4;
  f32x4 acc[4][4] = {};

  for (int kt = 0; kt < 1024; kt += 32) {
    __syncthreads();
#pragma unroll
    for (int i = 0; i < 2; i++) {
      int row = w * 32 + i * 16 + (l >> 2);
      gload_lds16(ao  + (size_t)(m0 + row) * 1024 + kt + (l & 3) * 8, A + w * 1024 + i * 512);
      gload_lds16(WpT + (size_t)(n0 + row) * 1024 + kt + (l & 3) * 8, B + w * 1024 + i * 512);
    }
    __syncthreads();
    h8 a[4], b[4];
#pragma unroll
    for (int m = 0; m < 4; m++) a[m] = *(h8*)&A[(wr + m * 16 + fr) * 32 + fq * 8];
#pragma unroll
    for (int n = 0; n < 4; n++) b[n] = *(h8*)&B[(wc + n * 16 + fr) * 32 + fq * 8];
#pragma unroll
    for (int m = 0; m < 4; m++)
#pragma unroll
      for (int n = 0; n < 4; n++) acc[m][n] = MFMA(a[m], b[n], acc[m][n]);
  }

#pragma unroll
  for (int m = 0; m < 4; m++)
#pragma unroll
    for (int n = 0; n < 4; n++)
#pragma unroll
      for (int j = 0; j < 4; j++) {
        int row = m0 + wr + m * 16 + fq * 4 + j;
        int col = n0 + wc + n * 16 + fr;
        out[(size_t)row * 1024 + col] = acc[m][n][j] + bias[col];
      }
}

// ---------------------------------------------------------------------------
extern "C" void kernel_launch(void* const* d_in, const int* in_sizes, int n_in,
                              void* d_out, int out_size, void* d_ws, size_t ws_size,
                              hipStream_t stream) {
  const float* x      = (const float*)d_in[0];
  const float* w_qkv  = (const float*)d_in[1];
  const float* b_qkv  = (const float*)d_in[2];
  const float* w_proj = (const float*)d_in[3];
  const float* b_proj = (const float*)d_in[4];

  float* out0 = (float*)d_out;
  float* att  = out0 + OUT0_SZ;            // [B,H,S,S] logits -> filtered_attn

  f16* ws16 = (f16*)d_ws;                  // 65.0 MB peak (< 67.1 MB proven)
  f16* WhiT = ws16;                        // [3072][1024]
  f16* WloT = ws16 +  3145728;
  f16* WpT  = ws16 +  6291456;             // [1024][1024]
  f16* Qhi  = ws16 +  7340032;             // [64][1024][64] each
  f16* Qlo  = ws16 + 11534336;
  f16* Khi  = ws16 + 15728640;
  f16* Klo  = ws16 + 19922944;
  f16* Vf   = ws16 + 24117248;             // [64][1024][64]
  f16* Vt   = ws16 + 28311552;             // [64][64][1024]
  f16* ao16 = ws16;                        // aliases WhiT/WloT (dead after qkv)

  transpose_split<1><<<dim3(96, 32), 256, 0, stream>>>(w_qkv, WhiT, WloT, 1024, 3072, 4096.f);
  transpose_split<0><<<dim3(32, 32), 256, 0, stream>>>(w_proj, WpT, nullptr, 1024, 1024, 1.f);
  qkv_gemm<<<dim3(24, 32), 256, 0, stream>>>(x, WhiT, WloT, b_qkv, Qhi, Qlo, Khi, Klo, Vf);
  transpose_v<<<dim3(32, 2, 64), 256, 0, stream>>>(Vf, Vt);
  qk_gemm<<<dim3(8, 8, 64), 256, 0, stream>>>(Qhi, Qlo, Khi, Klo, att);
  softmax_filter<<<64 * SS, 256, 0, stream>>>(att);
  pv_gemm<<<dim3(8, 64), 256, 0, stream>>>(att, Vt, ao16);
  proj_gemm<<<dim3(8, 32), 256, 0, stream>>>(ao16, WpT, b_proj, out0);
}